// Round 14
// baseline (688.928 us; speedup 1.0000x reference)
//
#include <hip/hip_runtime.h>
#include <math.h>

#define N_NODES 50000
#define N_EDGES 800000
#define NUM_GRAPHS 256
#define NPADROWS 50048   // 1564*32
#define CAP 64           // CSR capacity per node (max observed degree ~35)
#define SCLN -1.44269504088896f  // -log2(e): f-side scale, exp2(SCLN*x)=exp(-x)
#define SCLP 1.44269504088896f   // +log2(e): s-side scale
#define C693 0.69314718056f
#define LROW 264         // LDS staging row stride in u16 (528 B)

typedef __attribute__((ext_vector_type(8))) short short8;
typedef __attribute__((ext_vector_type(4))) float f32x4;
typedef __attribute__((ext_vector_type(2))) float f32x2;

__device__ __forceinline__ float fast_rcp(float x) {
#if __has_builtin(__builtin_amdgcn_rcpf)
  return __builtin_amdgcn_rcpf(x);
#else
  return 1.0f / x;
#endif
}
__device__ __forceinline__ float EX2(float x) {
#if __has_builtin(__builtin_amdgcn_exp2f)
  return __builtin_amdgcn_exp2f(x);
#else
  return exp2f(x);
#endif
}
__device__ __forceinline__ float LG2(float x) {
#if __has_builtin(__builtin_amdgcn_logf)
  return __builtin_amdgcn_logf(x);  // log2
#else
  return log2f(x);
#endif
}
// round-to-nearest-even (prep path, cold)
__device__ __forceinline__ unsigned f2bf(float x) {
  unsigned u = __float_as_uint(x);
  return (u + 0x7fffu + ((u >> 16) & 1u)) >> 16;
}
// round-half-up bf16: 1 VALU op
__device__ __forceinline__ unsigned short bfr(float v) {
  return (unsigned short)((__float_as_uint(v) + 0x8000u) >> 16);
}
__device__ __forceinline__ unsigned pkbfr(float lo, float hi) {
  unsigned a = (__float_as_uint(lo) + 0x8000u) >> 16;
  unsigned b = (__float_as_uint(hi) + 0x8000u) & 0xffff0000u;
  return a | b;
}
__device__ __forceinline__ float u2f(unsigned u) { return __uint_as_float(u); }
__device__ __forceinline__ f32x2 mk2(float a, float b) {
  f32x2 r; r.x = a; r.y = b; return r;
}
// unpack u32 holding (lo u16 -> ch0 bf16, hi u16 -> ch1 bf16) to f32x2
__device__ __forceinline__ f32x2 unp(unsigned u) {
  return mk2(u2f(u << 16), u2f(u & 0xffff0000u));
}
// msg pair: sigm (exp2 dom, gf pre-scaled -log2e) * softplus (gs pre-scaled +log2e)
// HARDWARE trans (R10's polynomial replacement regressed 77->127 us).
__device__ __forceinline__ void edge_ch2(f32x2 gf, f32x2 gs, float cmul, f32x2& acc) {
  f32x2 den = mk2(EX2(gf.x), EX2(gf.y)) + 1.0f;
  f32x2 lg = mk2(LG2(1.0f + EX2(-fabsf(gs.x))), LG2(1.0f + EX2(-fabsf(gs.y))));
  f32x2 sp = lg + __builtin_elementwise_max(gs, (f32x2)0.0f);
  f32x2 rt = mk2(fast_rcp(den.x), fast_rcp(den.y)) * sp;
  acc = __builtin_elementwise_fma(rt, (f32x2)cmul, acc);
}

// bf16 x rows, ch128 fp32, pos4, and cnt-zero in one pass (64 thr/node)
__global__ void init_x(const int* __restrict__ atoms, const float* __restrict__ pos,
                       const float* __restrict__ emb, float* __restrict__ x128c,
                       unsigned* __restrict__ xbu, float4* __restrict__ pos4,
                       int* __restrict__ cnt) {
  int n = blockIdx.x;
  int t = threadIdx.x;
  int a = atoms[n];
  float2 e = *(const float2*)(emb + (size_t)a * 128 + 2 * t);
  xbu[(size_t)n * 64 + t] = f2bf(e.x) | (f2bf(e.y) << 16);
  if (t == 0) x128c[n] = pos[n * 3 + 2];
  if (t == 1) pos4[n] = make_float4(pos[3 * n], pos[3 * n + 1], pos[3 * n + 2], 0.f);
  if (t == 2) cnt[n] = 0;
}

// B (pre-scaled by SCLN/SCLP) in MFMA fragment order + Wtail (scale*w1, scale*bias).
__global__ void prep_b(const float* __restrict__ Wf, const float* __restrict__ Ws,
                       const float* __restrict__ bfp, const float* __restrict__ bsp,
                       uint4* __restrict__ Bp, float2* __restrict__ Wtail) {
  int idx = blockIdx.x * 256 + threadIdx.x;
  if (idx < 5 * 4 * 9 * 4 * 64) {
    int lane = idx & 63;
    int t = idx >> 6;
    int ks = t & 3; t >>= 2;
    int ct = t % 9; t /= 9;
    int g = t & 3;
    int l = t >> 2;
    const float* W = (g >= 2) ? Ws : Wf;
    float sc = (g < 2) ? SCLN : SCLP;  // scale folded into B -> MFMA acc pre-scaled
    int col = ct * 16 + (lane & 15);
    int kb = ks * 32 + (lane >> 4) * 8;
    unsigned u[4];
#pragma unroll
    for (int p = 0; p < 4; ++p) {
      unsigned lo = 0, hi = 0;
      if (col < 129) {
        int k0 = kb + 2 * p, k1 = k0 + 1;
        int r0 = (g & 1) ? 129 + k0 : k0;
        int r1 = (g & 1) ? 129 + k1 : k1;
        lo = f2bf(sc * W[(size_t)(l * 259 + r0) * 129 + col]);
        hi = f2bf(sc * W[(size_t)(l * 259 + r1) * 129 + col]);
      }
      u[p] = lo | (hi << 16);
    }
    Bp[idx] = make_uint4(u[0], u[1], u[2], u[3]);
  } else {
    int j = idx - 5 * 4 * 9 * 4 * 64;
    if (j >= 5 * 4 * 144) return;
    int c = j % 144;
    int t = j / 144;
    int g = t & 3;
    int l = t >> 2;
    float sc = (g < 2) ? SCLN : SCLP;
    float w1 = 0.0f, bias = 0.0f;
    if (c <= 128) {
      const float* W = (g >= 2) ? Ws : Wf;
      int row = (g & 1) ? 257 : 128;
      w1 = sc * W[(size_t)(l * 259 + row) * 129 + c];
      if (g == 0) bias = SCLN * bfp[l * 129 + c];
      if (g == 2) bias = SCLP * bsp[l * 129 + c];
    }
    Wtail[(l * 4 + g) * 144 + c] = make_float2(w1, bias);
  }
}

// edge CSR build; threads <= N_NODES also emit graph offsets
__global__ void build_csr(const int* __restrict__ ei, const float4* __restrict__ pos4,
                          const int* __restrict__ batch, int* __restrict__ cnt,
                          int2* __restrict__ csr, int* __restrict__ goff) {
  int e = blockIdx.x * 256 + threadIdx.x;
  if (e <= N_NODES) {
    int b = (e < N_NODES) ? batch[e] : NUM_GRAPHS;
    int bp = (e > 0) ? batch[e - 1] : -1;
    for (int g = bp + 1; g <= b; ++g) goff[g] = e;
  }
  if (e >= N_EDGES) return;
  int s = ei[e];
  int d = ei[N_EDGES + e];
  float4 ps = pos4[s];
  float4 pd = pos4[d];
  float dx = ps.x - pd.x, dy = ps.y - pd.y, dz = ps.z - pd.z;
  float ea = sqrtf(dx * dx + dy * dy + dz * dz);
  int p = atomicAdd(&cnt[d], 1);
  if (p < CAP) csr[d * CAP + p] = make_int2(s, __float_as_int(ea));
}

// 32 rows x (4 groups x 144 cols) per block; wave w = group w.
// B pre-scaled: acc comes out of MFMA already in the exp2 domain scale.
// u16 row layout (256 u16): [f(2c),f(2c+1),s(2c),s(2c+1)] at c*4 — Pdh dst, Pfs src.
// Dual LDS images, single writeback pass (R12's two-phase shared image regressed).
__global__ __launch_bounds__(256) void gemm_mfma(
    const unsigned* __restrict__ xbu, const float* __restrict__ x128c,
    const uint4* __restrict__ Bp, const float2* __restrict__ Wtail,
    unsigned short* __restrict__ Pdh, unsigned short* __restrict__ Pfs,
    unsigned* __restrict__ Pd128c, unsigned* __restrict__ Pc128, int layer) {
  __shared__ short smA[32 * 136];             // A staging, row stride 136 shorts
  __shared__ unsigned short ldsD[32 * LROW];  // dst row image (f+s interleaved)
  __shared__ unsigned short ldsS[32 * LROW];  // src row image
  int n0 = blockIdx.x * 32;
  int tid = threadIdx.x;
  for (int ch = tid; ch < 512; ch += 256) {
    int row = ch >> 4, cq = ch & 15;
    *(uint4*)(&smA[row * 136 + cq * 8]) =
        *(const uint4*)(xbu + (size_t)(n0 + row) * 64 + cq * 4);
  }
  __syncthreads();
  int g = tid >> 6;
  int l = tid & 63;
  int q = l >> 4, c16 = l & 15;
  const short8* Bp8 = (const short8*)Bp;
  int bbase = (layer * 4 + g) * 9 * 4;
  f32x4 acc[2][9];
#pragma unroll
  for (int rt = 0; rt < 2; ++rt)
#pragma unroll
    for (int ct = 0; ct < 9; ++ct) acc[rt][ct] = (f32x4){0.f, 0.f, 0.f, 0.f};
#pragma unroll
  for (int ks = 0; ks < 4; ++ks) {
    short8 a0 = *(const short8*)(&smA[c16 * 136 + (ks * 4 + q) * 8]);
    short8 a1 = *(const short8*)(&smA[(16 + c16) * 136 + (ks * 4 + q) * 8]);
#pragma unroll
    for (int ct = 0; ct < 9; ++ct) {
      short8 b = Bp8[(size_t)(bbase + ct * 4 + ks) * 64 + l];
      acc[0][ct] = __builtin_amdgcn_mfma_f32_16x16x32_bf16(a0, b, acc[0][ct], 0, 0, 0);
      acc[1][ct] = __builtin_amdgcn_mfma_f32_16x16x32_bf16(a1, b, acc[1][ct], 0, 0, 0);
    }
  }
  const float2* Wt = Wtail + (layer * 4 + g) * 144;
  float x128[2][4];
#pragma unroll
  for (int rt = 0; rt < 2; ++rt)
#pragma unroll
    for (int r = 0; r < 4; ++r)
      x128[rt][r] = x128c[n0 + rt * 16 + q * 4 + r];  // contiguous, L1-hit
  unsigned short* ldsO = (g & 1) ? ldsS : ldsD;
  int soff = (g >= 2) ? 2 : 0;
  unsigned short* c128p = (g & 1) ? (unsigned short*)Pc128 : (unsigned short*)Pd128c;
  int c128o = (g >= 2) ? 1 : 0;
#pragma unroll
  for (int ct = 0; ct < 9; ++ct) {
    int col = ct * 16 + c16;
    float2 wb = Wt[col];  // (scale*w1, scale*bias)
#pragma unroll
    for (int rt = 0; rt < 2; ++rt) {
#pragma unroll
      for (int r = 0; r < 4; ++r) {
        int rl = rt * 16 + q * 4 + r;  // local row
        float v = acc[rt][ct][r] + fmaf(x128[rt][r], wb.x, wb.y);
        if (col < 128) {
          ldsO[rl * LROW + ((col >> 1) << 2) + soff + (col & 1)] = bfr(v);
        } else if (col == 128) {
          c128p[2 * (size_t)(n0 + rl) + c128o] = bfr(v);
        }
      }
    }
  }
  __syncthreads();
  // coalesced writeback: 2048 16B-chunks (1024 per image), 8 rounds of 256 thr
#pragma unroll
  for (int i = tid; i < 2048; i += 256) {
    int img = i >> 10;
    int c = i & 1023;
    int row = c >> 5, part = c & 31;
    const unsigned short* src = (img ? ldsS : ldsD) + row * LROW + part * 8;
    unsigned short* dst = (img ? Pfs : Pdh) + (size_t)(n0 + row) * 256 + part * 8;
    *(uint4*)dst = *(const uint4*)src;
  }
}

// one wave per dst node. Lanes 0-31: even edges, 32-63: odd edges; each lane 4 channels
// via one uint4 gather. Wave-uniform CSR pair loads (scalar pipe) + selects.
// Depth-2 prefetch: two gathers in flight covers HBM-miss latency (~900 cyc) against
// the ~390-cyc compute body. Residual carried in bf16 xbu; fp32 only for ch-128.
__global__ __launch_bounds__(256) void edge_agg(
    const unsigned short* __restrict__ Pdh, const unsigned short* __restrict__ Pfs,
    const unsigned* __restrict__ Pd128c, const unsigned* __restrict__ Pc128,
    unsigned* __restrict__ xbu, float* __restrict__ x128c, const int* __restrict__ cnt,
    const int2* __restrict__ csr, const float* __restrict__ WfL,
    const float* __restrict__ WsL) {
  int lane = threadIdx.x & 63;
  int half = lane >> 5;
  int l5 = lane & 31;
  int n = blockIdx.x * 4 + (threadIdx.x >> 6);
  if (n >= N_NODES) return;
  int nu = __builtin_amdgcn_readfirstlane(n);  // wave-uniform -> scalar pipe
  const float* wfl = WfL + 258 * 129;
  const float* wsl = WsL + 258 * 129;
  uint4 pdv = *(const uint4*)(Pdh + (size_t)nu * 256 + 8 * l5);
  f32x2 bfa = unp(pdv.x), bsa = unp(pdv.y), bfb = unp(pdv.z), bsb = unp(pdv.w);
  float2 wfa0 = *(const float2*)(wfl + 4 * l5);
  float2 wfb0 = *(const float2*)(wfl + 4 * l5 + 2);
  float2 wsa0 = *(const float2*)(wsl + 4 * l5);
  float2 wsb0 = *(const float2*)(wsl + 4 * l5 + 2);
  f32x2 wfa = mk2(SCLN * wfa0.x, SCLN * wfa0.y), wfb = mk2(SCLN * wfb0.x, SCLN * wfb0.y);
  f32x2 wsa = mk2(SCLP * wsa0.x, SCLP * wsa0.y), wsb = mk2(SCLP * wsb0.x, SCLP * wsb0.y);
  unsigned pd1 = Pd128c[nu];
  float bfc8 = u2f(pd1 << 16), bsc8 = u2f(pd1 & 0xffff0000u);
  float wfc8 = SCLN * wfl[128], wsc8 = SCLP * wsl[128];
  int m = cnt[nu];
  if (m > CAP) m = CAP;
  const int4* cb4 = (const int4*)(csr + (size_t)nu * CAP);  // wave-uniform pair load
  const uint4* Pfq = (const uint4*)Pfs;
  float maskC = half ? 0.0f : C693;
  f32x2 accA = (f32x2)0.0f, accB = (f32x2)0.0f;

#define GATHER(qq) Pfq[(size_t)(half ? qq.z : qq.x) * 32 + l5]
#define COMPUTE(qq, gg, CM)                                                    \
  {                                                                            \
    f32x2 ea_ = (f32x2)__int_as_float(half ? qq.w : qq.y);                     \
    edge_ch2(__builtin_elementwise_fma(ea_, wfa, bfa + unp(gg.x)),             \
             __builtin_elementwise_fma(ea_, wsa, bsa + unp(gg.y)), CM, accA);  \
    edge_ch2(__builtin_elementwise_fma(ea_, wfb, bfb + unp(gg.z)),             \
             __builtin_elementwise_fma(ea_, wsb, bsb + unp(gg.w)), CM, accB);  \
  }

  int Pf = m >> 1;
  int4 q0 = make_int4(0, 0, 0, 0), q1 = make_int4(0, 0, 0, 0);
  uint4 g0 = make_uint4(0, 0, 0, 0), g1 = make_uint4(0, 0, 0, 0);
  if (Pf > 0) {
    q0 = cb4[0];
    g0 = GATHER(q0);
  }
  if (Pf > 1) {
    q1 = cb4[1];
    g1 = GATHER(q1);
  }
  for (int p = 0; p < Pf; ++p) {
    int4 qn = q1;
    uint4 gn = g1;
    if (p + 2 < Pf) {
      qn = cb4[p + 2];
      gn = GATHER(qn);
    }
    COMPUTE(q0, g0, C693);
    q0 = q1;
    g0 = g1;
    q1 = qn;
    g1 = gn;
  }
  if (m & 1) {  // last edge: both halves compute it, half 1 masked to zero
    int4 qt = cb4[Pf];
    f32x2 ea_ = (f32x2)__int_as_float(qt.y);
    uint4 gt = Pfq[(size_t)qt.x * 32 + l5];
    edge_ch2(__builtin_elementwise_fma(ea_, wfa, bfa + unp(gt.x)),
             __builtin_elementwise_fma(ea_, wsa, bsa + unp(gt.y)), maskC, accA);
    edge_ch2(__builtin_elementwise_fma(ea_, wfb, bfb + unp(gt.z)),
             __builtin_elementwise_fma(ea_, wsb, bsb + unp(gt.w)), maskC, accB);
  }
#undef GATHER
#undef COMPUTE

  // combine halves
  accA.x += __shfl_xor(accA.x, 32, 64);
  accA.y += __shfl_xor(accA.y, 32, 64);
  accB.x += __shfl_xor(accB.x, 32, 64);
  accB.y += __shfl_xor(accB.y, 32, 64);

  // channel 128: lanes parallel over edges (deg <= 64), single u32 gather, reduce
  float v2 = 0.f;
  if (lane < m) {
    int2 se = csr[(size_t)nu * CAP + lane];
    float ea = __int_as_float(se.y);
    unsigned pc = Pc128[se.x];
    float f2 = u2f(pc << 16), s2 = u2f(pc & 0xffff0000u);
    float gf2 = fmaf(ea, wfc8, bfc8 + f2);
    float gs2 = fmaf(ea, wsc8, bsc8 + s2);
    float sp2 = LG2(1.0f + EX2(-fabsf(gs2))) + fmaxf(gs2, 0.0f);
    v2 = C693 * fast_rcp(1.0f + EX2(gf2)) * sp2;
  }
#pragma unroll
  for (int off = 32; off; off >>= 1) v2 += __shfl_down(v2, off, 64);

  if (half == 0) {
    uint2 xv = *(const uint2*)(xbu + (size_t)nu * 64 + 2 * l5);
    f32x2 xa = unp(xv.x) + accA;
    f32x2 xb = unp(xv.y) + accB;
    *(uint2*)(xbu + (size_t)nu * 64 + 2 * l5) =
        make_uint2(pkbfr(xa.x, xa.y), pkbfr(xb.x, xb.y));
  }
  if (lane == 0) x128c[nu] += v2;
}

// 4 partial blocks per graph, disjoint writes (no atomics, no pre-zero)
__global__ void pool2(const unsigned* __restrict__ xbu, const float* __restrict__ x128c,
                      const int* __restrict__ goff, float* __restrict__ gpart) {
  int gph = blockIdx.x >> 2;
  int q = blockIdx.x & 3;
  int t = threadIdx.x;
  if (t >= 129) return;
  int s = goff[gph], e = goff[gph + 1];
  int len = e - s;
  int chunk = (len + 3) >> 2;
  int a = s + q * chunk;
  int b = a + chunk; if (b > e) b = e;
  float acc = 0.f;
  if (t < 128) {
    int w = t >> 1, hi = t & 1;
    for (int n = a; n < b; ++n) {
      unsigned u = xbu[(size_t)n * 64 + w];
      acc += hi ? u2f(u & 0xffff0000u) : u2f(u << 16);
    }
  } else {
    for (int n = a; n < b; ++n) acc += x128c[n];
  }
  gpart[(size_t)(gph * 4 + q) * 132 + t] = acc;  // unconditional (ws is poisoned)
}

// fused: partial-sum + mean-divide + fc1 + fc2 + fc3 + out. one block per graph.
__global__ void fcout(const float* __restrict__ gpart, const int* __restrict__ goff,
                      const float* __restrict__ Wfc, const float* __restrict__ bfc,
                      const float* __restrict__ Wout, const float* __restrict__ bout,
                      float* __restrict__ out) {
  __shared__ float buf[2][132];
  __shared__ float red[3];
  int i = blockIdx.x;
  int t = threadIdx.x;
  int len = goff[i + 1] - goff[i];
  float inv = fast_rcp(fmaxf((float)len, 1.0f));
  if (t < 129) {
    float v = gpart[(size_t)(i * 4 + 0) * 132 + t] + gpart[(size_t)(i * 4 + 1) * 132 + t] +
              gpart[(size_t)(i * 4 + 2) * 132 + t] + gpart[(size_t)(i * 4 + 3) * 132 + t];
    buf[0][t] = v * inv;
  }
  __syncthreads();
  int cur = 0;
#pragma unroll
  for (int l = 0; l < 3; ++l) {
    float s = 0.f;
    if (t < 129) {
      s = bfc[l * 129 + t];
      const float* W = Wfc + (size_t)l * 129 * 129;
#pragma unroll 4
      for (int k = 0; k < 129; ++k) s += buf[cur][k] * W[k * 129 + t];
    }
    __syncthreads();
    if (t < 129) buf[1 - cur][t] = s;
    cur = 1 - cur;
    __syncthreads();
  }
  float p = (t < 129) ? buf[cur][t] * Wout[t] : 0.f;
#pragma unroll
  for (int off = 32; off; off >>= 1) p += __shfl_down(p, off, 64);
  if ((t & 63) == 0) red[t >> 6] = p;
  __syncthreads();
  if (t == 0) out[i] = red[0] + red[1] + red[2] + bout[0];
}

extern "C" void kernel_launch(void* const* d_in, const int* in_sizes, int n_in,
                              void* d_out, int out_size, void* d_ws, size_t ws_size,
                              hipStream_t stream) {
  const int* atoms = (const int*)d_in[0];
  const float* pos = (const float*)d_in[1];
  const int* ei = (const int*)d_in[2];
  const int* batch = (const int*)d_in[3];
  const float* emb = (const float*)d_in[4];
  const float* Wf = (const float*)d_in[5];
  const float* bfp = (const float*)d_in[6];
  const float* Ws = (const float*)d_in[7];
  const float* bsp = (const float*)d_in[8];
  const float* Wfc = (const float*)d_in[9];
  const float* bfc = (const float*)d_in[10];
  const float* Wout = (const float*)d_in[11];
  const float* bout = (const float*)d_in[12];
  float* outp = (float*)d_out;

  // workspace layout (every array 16B-aligned by construction)
  uint4* Bp = (uint4*)d_ws;                                   // 46080 uint4
  unsigned* xbu = (unsigned*)(Bp + 46080);                    // NPADROWS*64 u32
  unsigned short* Pdh = (unsigned short*)(xbu + (size_t)NPADROWS * 64);  // NPADROWS*256
  unsigned short* Pfs = Pdh + (size_t)NPADROWS * 256;         // NPADROWS*256
  float4* pos4 = (float4*)(Pfs + (size_t)NPADROWS * 256);     // N_NODES float4
  float2* Wtail = (float2*)(pos4 + N_NODES);                  // 5*4*144 float2
  float* x128c = (float*)(Wtail + 5 * 4 * 144);               // NPADROWS f32
  float* gpart = x128c + NPADROWS;                            // 256*4*132 f32
  int* goff = (int*)(gpart + 256 * 4 * 132);                  // 260 (padded)
  int* cnt = goff + 260;                                      // N_NODES (+pad)
  int2* csr = (int2*)(cnt + N_NODES + 4);                     // N_NODES*CAP (16B-aligned)
  unsigned* Pd128c = (unsigned*)(csr + (size_t)N_NODES * CAP);  // NPADROWS u32
  unsigned* Pc128 = Pd128c + NPADROWS;                        // NPADROWS u32

  init_x<<<N_NODES, 64, 0, stream>>>(atoms, pos, emb, x128c, xbu, pos4, cnt);
  prep_b<<<(5 * 4 * 9 * 4 * 64 + 5 * 4 * 144 + 255) / 256, 256, 0, stream>>>(
      Wf, Ws, bfp, bsp, Bp, Wtail);
  build_csr<<<(N_EDGES + 255) / 256, 256, 0, stream>>>(ei, pos4, batch, cnt, csr, goff);

  for (int l = 0; l < 5; ++l) {
    gemm_mfma<<<NPADROWS / 32, 256, 0, stream>>>(xbu, x128c, Bp, Wtail, Pdh, Pfs,
                                                 Pd128c, Pc128, l);
    edge_agg<<<(N_NODES + 3) / 4, 256, 0, stream>>>(Pdh, Pfs, Pd128c, Pc128, xbu, x128c,
                                                    cnt, csr,
                                                    Wf + (size_t)l * 259 * 129,
                                                    Ws + (size_t)l * 259 * 129);
  }

  pool2<<<NUM_GRAPHS * 4, 192, 0, stream>>>(xbu, x128c, goff, gpart);
  fcout<<<NUM_GRAPHS, 192, 0, stream>>>(gpart, goff, Wfc, bfc, Wout, bout, outp);
}

// Round 15
// 681.178 us; speedup vs baseline: 1.0114x; 1.0114x over previous
//
#include <hip/hip_runtime.h>
#include <math.h>

#define N_NODES 50000
#define N_EDGES 800000
#define NUM_GRAPHS 256
#define NPADROWS 50048   // 1564*32
#define CAP 64           // CSR capacity per node (max observed degree ~35)
#define SCLN -1.44269504088896f  // -log2(e): f-side scale, exp2(SCLN*x)=exp(-x)
#define SCLP 1.44269504088896f   // +log2(e): s-side scale
#define C693 0.69314718056f
#define LROW 264         // LDS staging row stride in u16 (528 B)

typedef __attribute__((ext_vector_type(8))) short short8;
typedef __attribute__((ext_vector_type(4))) float f32x4;
typedef __attribute__((ext_vector_type(2))) float f32x2;

__device__ __forceinline__ float fast_rcp(float x) {
#if __has_builtin(__builtin_amdgcn_rcpf)
  return __builtin_amdgcn_rcpf(x);
#else
  return 1.0f / x;
#endif
}
__device__ __forceinline__ float EX2(float x) {
#if __has_builtin(__builtin_amdgcn_exp2f)
  return __builtin_amdgcn_exp2f(x);
#else
  return exp2f(x);
#endif
}
__device__ __forceinline__ float LG2(float x) {
#if __has_builtin(__builtin_amdgcn_logf)
  return __builtin_amdgcn_logf(x);  // log2
#else
  return log2f(x);
#endif
}
// round-to-nearest-even (prep path, cold)
__device__ __forceinline__ unsigned f2bf(float x) {
  unsigned u = __float_as_uint(x);
  return (u + 0x7fffu + ((u >> 16) & 1u)) >> 16;
}
// round-half-up bf16: 1 VALU op
__device__ __forceinline__ unsigned short bfr(float v) {
  return (unsigned short)((__float_as_uint(v) + 0x8000u) >> 16);
}
__device__ __forceinline__ unsigned pkbfr(float lo, float hi) {
  unsigned a = (__float_as_uint(lo) + 0x8000u) >> 16;
  unsigned b = (__float_as_uint(hi) + 0x8000u) & 0xffff0000u;
  return a | b;
}
__device__ __forceinline__ float u2f(unsigned u) { return __uint_as_float(u); }
__device__ __forceinline__ f32x2 mk2(float a, float b) {
  f32x2 r; r.x = a; r.y = b; return r;
}
// unpack u32 holding (lo u16 -> ch0 bf16, hi u16 -> ch1 bf16) to f32x2
__device__ __forceinline__ f32x2 unp(unsigned u) {
  return mk2(u2f(u << 16), u2f(u & 0xffff0000u));
}
// msg pair: sigm (exp2 dom, gf pre-scaled -log2e) * softplus (gs pre-scaled +log2e)
// HARDWARE trans (R10's polynomial replacement regressed 77->127 us).
__device__ __forceinline__ void edge_ch2(f32x2 gf, f32x2 gs, float cmul, f32x2& acc) {
  f32x2 den = mk2(EX2(gf.x), EX2(gf.y)) + 1.0f;
  f32x2 lg = mk2(LG2(1.0f + EX2(-fabsf(gs.x))), LG2(1.0f + EX2(-fabsf(gs.y))));
  f32x2 sp = lg + __builtin_elementwise_max(gs, (f32x2)0.0f);
  f32x2 rt = mk2(fast_rcp(den.x), fast_rcp(den.y)) * sp;
  acc = __builtin_elementwise_fma(rt, (f32x2)cmul, acc);
}

// bf16 x rows, ch128 fp32, pos4, and cnt-zero in one pass (64 thr/node)
__global__ void init_x(const int* __restrict__ atoms, const float* __restrict__ pos,
                       const float* __restrict__ emb, float* __restrict__ x128c,
                       unsigned* __restrict__ xbu, float4* __restrict__ pos4,
                       int* __restrict__ cnt) {
  int n = blockIdx.x;
  int t = threadIdx.x;
  int a = atoms[n];
  float2 e = *(const float2*)(emb + (size_t)a * 128 + 2 * t);
  xbu[(size_t)n * 64 + t] = f2bf(e.x) | (f2bf(e.y) << 16);
  if (t == 0) x128c[n] = pos[n * 3 + 2];
  if (t == 1) pos4[n] = make_float4(pos[3 * n], pos[3 * n + 1], pos[3 * n + 2], 0.f);
  if (t == 2) cnt[n] = 0;
}

// B (pre-scaled by SCLN/SCLP) in MFMA fragment order + Wtail (scale*w1, scale*bias).
__global__ void prep_b(const float* __restrict__ Wf, const float* __restrict__ Ws,
                       const float* __restrict__ bfp, const float* __restrict__ bsp,
                       uint4* __restrict__ Bp, float2* __restrict__ Wtail) {
  int idx = blockIdx.x * 256 + threadIdx.x;
  if (idx < 5 * 4 * 9 * 4 * 64) {
    int lane = idx & 63;
    int t = idx >> 6;
    int ks = t & 3; t >>= 2;
    int ct = t % 9; t /= 9;
    int g = t & 3;
    int l = t >> 2;
    const float* W = (g >= 2) ? Ws : Wf;
    float sc = (g < 2) ? SCLN : SCLP;  // scale folded into B -> MFMA acc pre-scaled
    int col = ct * 16 + (lane & 15);
    int kb = ks * 32 + (lane >> 4) * 8;
    unsigned u[4];
#pragma unroll
    for (int p = 0; p < 4; ++p) {
      unsigned lo = 0, hi = 0;
      if (col < 129) {
        int k0 = kb + 2 * p, k1 = k0 + 1;
        int r0 = (g & 1) ? 129 + k0 : k0;
        int r1 = (g & 1) ? 129 + k1 : k1;
        lo = f2bf(sc * W[(size_t)(l * 259 + r0) * 129 + col]);
        hi = f2bf(sc * W[(size_t)(l * 259 + r1) * 129 + col]);
      }
      u[p] = lo | (hi << 16);
    }
    Bp[idx] = make_uint4(u[0], u[1], u[2], u[3]);
  } else {
    int j = idx - 5 * 4 * 9 * 4 * 64;
    if (j >= 5 * 4 * 144) return;
    int c = j % 144;
    int t = j / 144;
    int g = t & 3;
    int l = t >> 2;
    float sc = (g < 2) ? SCLN : SCLP;
    float w1 = 0.0f, bias = 0.0f;
    if (c <= 128) {
      const float* W = (g >= 2) ? Ws : Wf;
      int row = (g & 1) ? 257 : 128;
      w1 = sc * W[(size_t)(l * 259 + row) * 129 + c];
      if (g == 0) bias = SCLN * bfp[l * 129 + c];
      if (g == 2) bias = SCLP * bsp[l * 129 + c];
    }
    Wtail[(l * 4 + g) * 144 + c] = make_float2(w1, bias);
  }
}

// edge CSR build; threads <= N_NODES also emit graph offsets
__global__ void build_csr(const int* __restrict__ ei, const float4* __restrict__ pos4,
                          const int* __restrict__ batch, int* __restrict__ cnt,
                          int2* __restrict__ csr, int* __restrict__ goff) {
  int e = blockIdx.x * 256 + threadIdx.x;
  if (e <= N_NODES) {
    int b = (e < N_NODES) ? batch[e] : NUM_GRAPHS;
    int bp = (e > 0) ? batch[e - 1] : -1;
    for (int g = bp + 1; g <= b; ++g) goff[g] = e;
  }
  if (e >= N_EDGES) return;
  int s = ei[e];
  int d = ei[N_EDGES + e];
  float4 ps = pos4[s];
  float4 pd = pos4[d];
  float dx = ps.x - pd.x, dy = ps.y - pd.y, dz = ps.z - pd.z;
  float ea = sqrtf(dx * dx + dy * dy + dz * dz);
  int p = atomicAdd(&cnt[d], 1);
  if (p < CAP) csr[d * CAP + p] = make_int2(s, __float_as_int(ea));
}

// 32 rows x (4 groups x 144 cols) per block; wave w = group w.
// B pre-scaled: acc comes out of MFMA already in the exp2 domain scale.
// u16 row layout (256 u16): [f(2c),f(2c+1),s(2c),s(2c+1)] at c*4 — Pdh dst, Pfs src.
// Dual LDS images, single writeback pass.
__global__ __launch_bounds__(256) void gemm_mfma(
    const unsigned* __restrict__ xbu, const float* __restrict__ x128c,
    const uint4* __restrict__ Bp, const float2* __restrict__ Wtail,
    unsigned short* __restrict__ Pdh, unsigned short* __restrict__ Pfs,
    unsigned* __restrict__ Pd128c, unsigned* __restrict__ Pc128, int layer) {
  __shared__ short smA[32 * 136];             // A staging, row stride 136 shorts
  __shared__ unsigned short ldsD[32 * LROW];  // dst row image (f+s interleaved)
  __shared__ unsigned short ldsS[32 * LROW];  // src row image
  int n0 = blockIdx.x * 32;
  int tid = threadIdx.x;
  for (int ch = tid; ch < 512; ch += 256) {
    int row = ch >> 4, cq = ch & 15;
    *(uint4*)(&smA[row * 136 + cq * 8]) =
        *(const uint4*)(xbu + (size_t)(n0 + row) * 64 + cq * 4);
  }
  __syncthreads();
  int g = tid >> 6;
  int l = tid & 63;
  int q = l >> 4, c16 = l & 15;
  const short8* Bp8 = (const short8*)Bp;
  int bbase = (layer * 4 + g) * 9 * 4;
  f32x4 acc[2][9];
#pragma unroll
  for (int rt = 0; rt < 2; ++rt)
#pragma unroll
    for (int ct = 0; ct < 9; ++ct) acc[rt][ct] = (f32x4){0.f, 0.f, 0.f, 0.f};
#pragma unroll
  for (int ks = 0; ks < 4; ++ks) {
    short8 a0 = *(const short8*)(&smA[c16 * 136 + (ks * 4 + q) * 8]);
    short8 a1 = *(const short8*)(&smA[(16 + c16) * 136 + (ks * 4 + q) * 8]);
#pragma unroll
    for (int ct = 0; ct < 9; ++ct) {
      short8 b = Bp8[(size_t)(bbase + ct * 4 + ks) * 64 + l];
      acc[0][ct] = __builtin_amdgcn_mfma_f32_16x16x32_bf16(a0, b, acc[0][ct], 0, 0, 0);
      acc[1][ct] = __builtin_amdgcn_mfma_f32_16x16x32_bf16(a1, b, acc[1][ct], 0, 0, 0);
    }
  }
  const float2* Wt = Wtail + (layer * 4 + g) * 144;
  float x128[2][4];
#pragma unroll
  for (int rt = 0; rt < 2; ++rt)
#pragma unroll
    for (int r = 0; r < 4; ++r)
      x128[rt][r] = x128c[n0 + rt * 16 + q * 4 + r];  // contiguous, L1-hit
  unsigned short* ldsO = (g & 1) ? ldsS : ldsD;
  int soff = (g >= 2) ? 2 : 0;
  unsigned short* c128p = (g & 1) ? (unsigned short*)Pc128 : (unsigned short*)Pd128c;
  int c128o = (g >= 2) ? 1 : 0;
#pragma unroll
  for (int ct = 0; ct < 9; ++ct) {
    int col = ct * 16 + c16;
    float2 wb = Wt[col];  // (scale*w1, scale*bias)
#pragma unroll
    for (int rt = 0; rt < 2; ++rt) {
#pragma unroll
      for (int r = 0; r < 4; ++r) {
        int rl = rt * 16 + q * 4 + r;  // local row
        float v = acc[rt][ct][r] + fmaf(x128[rt][r], wb.x, wb.y);
        if (col < 128) {
          ldsO[rl * LROW + ((col >> 1) << 2) + soff + (col & 1)] = bfr(v);
        } else if (col == 128) {
          c128p[2 * (size_t)(n0 + rl) + c128o] = bfr(v);
        }
      }
    }
  }
  __syncthreads();
  // coalesced writeback: 2048 16B-chunks (1024 per image), 8 rounds of 256 thr
#pragma unroll
  for (int i = tid; i < 2048; i += 256) {
    int img = i >> 10;
    int c = i & 1023;
    int row = c >> 5, part = c & 31;
    const unsigned short* src = (img ? ldsS : ldsD) + row * LROW + part * 8;
    unsigned short* dst = (img ? Pfs : Pdh) + (size_t)(n0 + row) * 256 + part * 8;
    *(uint4*)dst = *(const uint4*)src;
  }
}

// one wave per dst node. Lanes 0-31: even edges, 32-63: odd edges; each lane 4 channels
// via one uint4 gather. Wave-uniform CSR pair loads (scalar pipe) + selects.
// Depth-1 prefetch [R13 optimum — depth-2 (R14) regressed: TLP already hides latency
// at ~65% occupancy; extra ILP only costs VGPRs]. Residual carried in bf16 xbu.
__global__ __launch_bounds__(256) void edge_agg(
    const unsigned short* __restrict__ Pdh, const unsigned short* __restrict__ Pfs,
    const unsigned* __restrict__ Pd128c, const unsigned* __restrict__ Pc128,
    unsigned* __restrict__ xbu, float* __restrict__ x128c, const int* __restrict__ cnt,
    const int2* __restrict__ csr, const float* __restrict__ WfL,
    const float* __restrict__ WsL) {
  int lane = threadIdx.x & 63;
  int half = lane >> 5;
  int l5 = lane & 31;
  int n = blockIdx.x * 4 + (threadIdx.x >> 6);
  if (n >= N_NODES) return;
  int nu = __builtin_amdgcn_readfirstlane(n);  // wave-uniform -> scalar pipe
  const float* wfl = WfL + 258 * 129;
  const float* wsl = WsL + 258 * 129;
  uint4 pdv = *(const uint4*)(Pdh + (size_t)nu * 256 + 8 * l5);
  f32x2 bfa = unp(pdv.x), bsa = unp(pdv.y), bfb = unp(pdv.z), bsb = unp(pdv.w);
  float2 wfa0 = *(const float2*)(wfl + 4 * l5);
  float2 wfb0 = *(const float2*)(wfl + 4 * l5 + 2);
  float2 wsa0 = *(const float2*)(wsl + 4 * l5);
  float2 wsb0 = *(const float2*)(wsl + 4 * l5 + 2);
  f32x2 wfa = mk2(SCLN * wfa0.x, SCLN * wfa0.y), wfb = mk2(SCLN * wfb0.x, SCLN * wfb0.y);
  f32x2 wsa = mk2(SCLP * wsa0.x, SCLP * wsa0.y), wsb = mk2(SCLP * wsb0.x, SCLP * wsb0.y);
  unsigned pd1 = Pd128c[nu];
  float bfc8 = u2f(pd1 << 16), bsc8 = u2f(pd1 & 0xffff0000u);
  float wfc8 = SCLN * wfl[128], wsc8 = SCLP * wsl[128];
  int m = cnt[nu];
  if (m > CAP) m = CAP;
  const int4* cb4 = (const int4*)(csr + (size_t)nu * CAP);  // wave-uniform pair load
  const uint4* Pfq = (const uint4*)Pfs;
  float maskC = half ? 0.0f : C693;
  f32x2 accA = (f32x2)0.0f, accB = (f32x2)0.0f;

#define GATHER(qq) Pfq[(size_t)(half ? qq.z : qq.x) * 32 + l5]
#define COMPUTE(qq, gg, CM)                                                    \
  {                                                                            \
    f32x2 ea_ = (f32x2)__int_as_float(half ? qq.w : qq.y);                     \
    edge_ch2(__builtin_elementwise_fma(ea_, wfa, bfa + unp(gg.x)),             \
             __builtin_elementwise_fma(ea_, wsa, bsa + unp(gg.y)), CM, accA);  \
    edge_ch2(__builtin_elementwise_fma(ea_, wfb, bfb + unp(gg.z)),             \
             __builtin_elementwise_fma(ea_, wsb, bsb + unp(gg.w)), CM, accB);  \
  }

  int Pf = m >> 1;
  int4 qc = make_int4(0, 0, 0, 0);
  uint4 gc = make_uint4(0, 0, 0, 0);
  if (Pf > 0) {
    qc = cb4[0];
    gc = GATHER(qc);
  }
  for (int p = 0; p < Pf; ++p) {
    int4 qn = qc;
    uint4 gn = gc;
    if (p + 1 < Pf) {
      qn = cb4[p + 1];
      gn = GATHER(qn);
    }
    COMPUTE(qc, gc, C693);
    qc = qn;
    gc = gn;
  }
  if (m & 1) {  // last edge: both halves compute it, half 1 masked to zero
    int4 qt = cb4[Pf];
    f32x2 ea_ = (f32x2)__int_as_float(qt.y);
    uint4 gt = Pfq[(size_t)qt.x * 32 + l5];
    edge_ch2(__builtin_elementwise_fma(ea_, wfa, bfa + unp(gt.x)),
             __builtin_elementwise_fma(ea_, wsa, bsa + unp(gt.y)), maskC, accA);
    edge_ch2(__builtin_elementwise_fma(ea_, wfb, bfb + unp(gt.z)),
             __builtin_elementwise_fma(ea_, wsb, bsb + unp(gt.w)), maskC, accB);
  }
#undef GATHER
#undef COMPUTE

  // combine halves
  accA.x += __shfl_xor(accA.x, 32, 64);
  accA.y += __shfl_xor(accA.y, 32, 64);
  accB.x += __shfl_xor(accB.x, 32, 64);
  accB.y += __shfl_xor(accB.y, 32, 64);

  // channel 128: lanes parallel over edges (deg <= 64), single u32 gather, reduce
  float v2 = 0.f;
  if (lane < m) {
    int2 se = csr[(size_t)nu * CAP + lane];
    float ea = __int_as_float(se.y);
    unsigned pc = Pc128[se.x];
    float f2 = u2f(pc << 16), s2 = u2f(pc & 0xffff0000u);
    float gf2 = fmaf(ea, wfc8, bfc8 + f2);
    float gs2 = fmaf(ea, wsc8, bsc8 + s2);
    float sp2 = LG2(1.0f + EX2(-fabsf(gs2))) + fmaxf(gs2, 0.0f);
    v2 = C693 * fast_rcp(1.0f + EX2(gf2)) * sp2;
  }
#pragma unroll
  for (int off = 32; off; off >>= 1) v2 += __shfl_down(v2, off, 64);

  if (half == 0) {
    uint2 xv = *(const uint2*)(xbu + (size_t)nu * 64 + 2 * l5);
    f32x2 xa = unp(xv.x) + accA;
    f32x2 xb = unp(xv.y) + accB;
    *(uint2*)(xbu + (size_t)nu * 64 + 2 * l5) =
        make_uint2(pkbfr(xa.x, xa.y), pkbfr(xb.x, xb.y));
  }
  if (lane == 0) x128c[nu] += v2;
}

// 4 partial blocks per graph, disjoint writes (no atomics, no pre-zero)
__global__ void pool2(const unsigned* __restrict__ xbu, const float* __restrict__ x128c,
                      const int* __restrict__ goff, float* __restrict__ gpart) {
  int gph = blockIdx.x >> 2;
  int q = blockIdx.x & 3;
  int t = threadIdx.x;
  if (t >= 129) return;
  int s = goff[gph], e = goff[gph + 1];
  int len = e - s;
  int chunk = (len + 3) >> 2;
  int a = s + q * chunk;
  int b = a + chunk; if (b > e) b = e;
  float acc = 0.f;
  if (t < 128) {
    int w = t >> 1, hi = t & 1;
    for (int n = a; n < b; ++n) {
      unsigned u = xbu[(size_t)n * 64 + w];
      acc += hi ? u2f(u & 0xffff0000u) : u2f(u << 16);
    }
  } else {
    for (int n = a; n < b; ++n) acc += x128c[n];
  }
  gpart[(size_t)(gph * 4 + q) * 132 + t] = acc;  // unconditional (ws is poisoned)
}

// fused: partial-sum + mean-divide + fc1 + fc2 + fc3 + out. one block per graph.
__global__ void fcout(const float* __restrict__ gpart, const int* __restrict__ goff,
                      const float* __restrict__ Wfc, const float* __restrict__ bfc,
                      const float* __restrict__ Wout, const float* __restrict__ bout,
                      float* __restrict__ out) {
  __shared__ float buf[2][132];
  __shared__ float red[3];
  int i = blockIdx.x;
  int t = threadIdx.x;
  int len = goff[i + 1] - goff[i];
  float inv = fast_rcp(fmaxf((float)len, 1.0f));
  if (t < 129) {
    float v = gpart[(size_t)(i * 4 + 0) * 132 + t] + gpart[(size_t)(i * 4 + 1) * 132 + t] +
              gpart[(size_t)(i * 4 + 2) * 132 + t] + gpart[(size_t)(i * 4 + 3) * 132 + t];
    buf[0][t] = v * inv;
  }
  __syncthreads();
  int cur = 0;
#pragma unroll
  for (int l = 0; l < 3; ++l) {
    float s = 0.f;
    if (t < 129) {
      s = bfc[l * 129 + t];
      const float* W = Wfc + (size_t)l * 129 * 129;
#pragma unroll 4
      for (int k = 0; k < 129; ++k) s += buf[cur][k] * W[k * 129 + t];
    }
    __syncthreads();
    if (t < 129) buf[1 - cur][t] = s;
    cur = 1 - cur;
    __syncthreads();
  }
  float p = (t < 129) ? buf[cur][t] * Wout[t] : 0.f;
#pragma unroll
  for (int off = 32; off; off >>= 1) p += __shfl_down(p, off, 64);
  if ((t & 63) == 0) red[t >> 6] = p;
  __syncthreads();
  if (t == 0) out[i] = red[0] + red[1] + red[2] + bout[0];
}

extern "C" void kernel_launch(void* const* d_in, const int* in_sizes, int n_in,
                              void* d_out, int out_size, void* d_ws, size_t ws_size,
                              hipStream_t stream) {
  const int* atoms = (const int*)d_in[0];
  const float* pos = (const float*)d_in[1];
  const int* ei = (const int*)d_in[2];
  const int* batch = (const int*)d_in[3];
  const float* emb = (const float*)d_in[4];
  const float* Wf = (const float*)d_in[5];
  const float* bfp = (const float*)d_in[6];
  const float* Ws = (const float*)d_in[7];
  const float* bsp = (const float*)d_in[8];
  const float* Wfc = (const float*)d_in[9];
  const float* bfc = (const float*)d_in[10];
  const float* Wout = (const float*)d_in[11];
  const float* bout = (const float*)d_in[12];
  float* outp = (float*)d_out;

  // workspace layout (every array 16B-aligned by construction)
  uint4* Bp = (uint4*)d_ws;                                   // 46080 uint4
  unsigned* xbu = (unsigned*)(Bp + 46080);                    // NPADROWS*64 u32
  unsigned short* Pdh = (unsigned short*)(xbu + (size_t)NPADROWS * 64);  // NPADROWS*256
  unsigned short* Pfs = Pdh + (size_t)NPADROWS * 256;         // NPADROWS*256
  float4* pos4 = (float4*)(Pfs + (size_t)NPADROWS * 256);     // N_NODES float4
  float2* Wtail = (float2*)(pos4 + N_NODES);                  // 5*4*144 float2
  float* x128c = (float*)(Wtail + 5 * 4 * 144);               // NPADROWS f32
  float* gpart = x128c + NPADROWS;                            // 256*4*132 f32
  int* goff = (int*)(gpart + 256 * 4 * 132);                  // 260 (padded)
  int* cnt = goff + 260;                                      // N_NODES (+pad)
  int2* csr = (int2*)(cnt + N_NODES + 4);                     // N_NODES*CAP (16B-aligned)
  unsigned* Pd128c = (unsigned*)(csr + (size_t)N_NODES * CAP);  // NPADROWS u32
  unsigned* Pc128 = Pd128c + NPADROWS;                        // NPADROWS u32

  init_x<<<N_NODES, 64, 0, stream>>>(atoms, pos, emb, x128c, xbu, pos4, cnt);
  prep_b<<<(5 * 4 * 9 * 4 * 64 + 5 * 4 * 144 + 255) / 256, 256, 0, stream>>>(
      Wf, Ws, bfp, bsp, Bp, Wtail);
  build_csr<<<(N_EDGES + 255) / 256, 256, 0, stream>>>(ei, pos4, batch, cnt, csr, goff);

  for (int l = 0; l < 5; ++l) {
    gemm_mfma<<<NPADROWS / 32, 256, 0, stream>>>(xbu, x128c, Bp, Wtail, Pdh, Pfs,
                                                 Pd128c, Pc128, l);
    edge_agg<<<(N_NODES + 3) / 4, 256, 0, stream>>>(Pdh, Pfs, Pd128c, Pc128, xbu, x128c,
                                                    cnt, csr,
                                                    Wf + (size_t)l * 259 * 129,
                                                    Ws + (size_t)l * 259 * 129);
  }

  pool2<<<NUM_GRAPHS * 4, 192, 0, stream>>>(xbu, x128c, goff, gpart);
  fcout<<<NUM_GRAPHS, 192, 0, stream>>>(gpart, goff, Wfc, bfc, Wout, bout, outp);
}